// Round 1
// 1353.595 us; speedup vs baseline: 1.0115x; 1.0115x over previous
//
#include <hip/hip_runtime.h>
#include <math.h>

#define BB 8
#define TT 1024
#define HDIM 1024
#define G3 3072   // 3*H
#define NCH 32    // scan chunks
#define TC 32     // steps per chunk (NCH*TC == TT)
#define TP (TT + 2)   // time-padded rows (zero row at 0 and TT+1)

// bank-group swizzle: chunk q of row r lives at 16B-slot (q ^ SW(r)) within the row.
#define SW(r) (((r) >> 1) & 3)

typedef __attribute__((ext_vector_type(8))) short bf16x8;   // 8 bf16 = 4 VGPRs
typedef __attribute__((ext_vector_type(4))) float f32x4;

__device__ __forceinline__ unsigned short f2bf(float f) {
  union { float f; unsigned int u; } c; c.f = f;
  unsigned int u = c.u;
  return (unsigned short)((u + 0x7FFFu + ((u >> 16) & 1u)) >> 16);
}

__device__ __forceinline__ void load_lds16(const void* g, void* l) {
  __builtin_amdgcn_global_load_lds(
      (const __attribute__((address_space(1))) void*)g,
      (__attribute__((address_space(3))) void*)l, 16, 0, 0);
}

// x [B,T,1024] fp32 -> padded bf16 [B][T+2][1024], rows 0 and T+1 zeroed
__global__ __launch_bounds__(256) void cvt_x_pad_kernel(const float* __restrict__ in,
                                                        unsigned short* __restrict__ out) {
  int b = blockIdx.y;
  int i = (blockIdx.x * 256 + threadIdx.x) * 4;   // within-batch padded elem idx
  int r = i >> 10;                                 // padded row 0..1025
  int c = i & 1023;
  ushort4 o = make_ushort4(0, 0, 0, 0);
  if (r >= 1 && r <= TT) {
    float4 v = *(const float4*)(in + ((size_t)b * TT + (r - 1)) * 1024 + c);
    o.x = f2bf(v.x); o.y = f2bf(v.y); o.z = f2bf(v.z); o.w = f2bf(v.w);
  }
  *(ushort4*)(out + (size_t)b * TP * 1024 + i) = o;
}

// zero the two boundary rows of the padded out0b buffer [B][T+2][2048]
__global__ __launch_bounds__(256) void zero_pad_kernel(unsigned short* __restrict__ p) {
  int i = blockIdx.x * 256 + threadIdx.x;  // 0 .. 2*B*2048-1
  int b = i >> 12;
  int r = (i >> 11) & 1;
  int c = i & 2047;
  p[((size_t)b * TP + (r ? (TT + 1) : 0)) * 2048 + c] = 0;
}

// w [3H, C, 3] fp32 -> wt [3][3H][C] bf16
template<int C>
__global__ __launch_bounds__(256) void cvt_w_kernel(const float* __restrict__ in,
                                                    unsigned short* __restrict__ out) {
  int o = blockIdx.x * 256 + threadIdx.x;  // 3*3072*C total
  int c = o & (C - 1);
  int jk = o / C;
  int j = jk % G3;
  int k = jk / G3;
  out[o] = f2bf(in[(size_t)j * (3 * C) + (size_t)c * 3 + k]);
}

// conv-gates via bf16 MFMA on time-PADDED input: x is [B][T+2][C] bf16 with zero
// boundary rows; padded row p corresponds to t = p-1.
// Double-buffered LDS + counted vmcnt + raw barriers (T3/T4 minimum schedule):
// per K-step: issue next-step global_load_lds into buf^1, s_waitcnt vmcnt(N)
// (N = this wave's calls/step, so current buf is complete but next-step loads
// stay in flight across both barriers), raw s_barrier, 48 MFMA, raw s_barrier.
template<int C>
__global__ __launch_bounds__(256) void conv_mfma_kernel(
    const unsigned short* __restrict__ x,   // [B][T+2][C] bf16, padded
    const unsigned short* __restrict__ wt,  // [3][3072][C] bf16
    const float* __restrict__ bias,         // [3072]
    float* __restrict__ g)                  // [B,T,3072]
{
  const int L    = blockIdx.x;
  const int xcd  = L & 7;
  const int sL   = L >> 3;
  const int jt   = xcd * 3 + (sL % 3);
  const int rest = sL / 3;          // 0..63
  const int t0 = (rest & 7) * 128;
  const int j0 = jt * 128;
  const int b  = rest >> 3;

  const int tid  = threadIdx.x;
  const int lane = tid & 63;
  const int wave = tid >> 6;
  const int wm = wave >> 1, wn = wave & 1;

  // A: 144 staged rows (padded rows t0 .. t0+143); compute uses rows 0..129
  // (t = t0-1 .. t0+128). Rows 130..143 are over-stage garbage, never read.
  __shared__ unsigned short As[2][144 * 32];
  __shared__ unsigned short Bs[2][384 * 32];   // [k][j_local][c]

  f32x4 acc[4][4];
  #pragma unroll
  for (int i = 0; i < 4; i++)
    #pragma unroll
    for (int u = 0; u < 4; u++) acc[i][u] = (f32x4){0.f, 0.f, 0.f, 0.f};

  const unsigned short* xb = x + (size_t)b * TP * C;
  const int srow  = lane >> 2;   // row within a 16-row staging call
  const int sslot = lane & 3;    // 16B slot within 64B row
  const int rq = lane >> 4;      // frag chunk (8 bf16)
  const int rl = lane & 15;      // frag row

  // stage one K-step (c0) into buffer sel.
  // per-wave global_load_lds calls: wave 3 -> 9 (2 A + 1 A-extra + 6 B), else 8.
  auto stage = [&](int sel, int c0) {
    unsigned short* Ab = &As[sel][0];
    unsigned short* Bb = &Bs[sel][0];
    #pragma unroll
    for (int cc = 0; cc < 2; ++cc) {
      int call  = wave * 2 + cc;
      int lrow0 = call << 4;
      int lrow  = lrow0 + srow;
      int q = sslot ^ SW(lrow);
      load_lds16(xb + (size_t)(t0 + lrow) * C + c0 + q * 8, Ab + lrow0 * 32);
    }
    if (wave == 3) {           // call 8: rows 128..143
      int lrow0 = 128;
      int lrow  = lrow0 + srow;
      int q = sslot ^ SW(lrow);
      load_lds16(xb + (size_t)(t0 + lrow) * C + c0 + q * 8, Ab + lrow0 * 32);
    }
    #pragma unroll
    for (int cc = 0; cc < 6; ++cc) {
      int R0 = (wave * 6 + cc) << 4;
      int R  = R0 + srow;
      int k = R >> 7;
      int j = R & 127;
      int q = sslot ^ SW(R);
      load_lds16(wt + (size_t)k * (G3 * C) + (size_t)(j0 + j) * C + c0 + q * 8,
                 Bb + R0 * 32);
    }
  };

  constexpr int NSTEP = C / 32;

  stage(0, 0);                 // prologue: fill buffer 0

  #pragma unroll 2
  for (int it = 0; it < NSTEP; ++it) {
    const int cur = it & 1;
    if (it + 1 < NSTEP) {
      stage(cur ^ 1, (it + 1) * 32);       // prefetch next step
      // wait until only the just-issued calls are outstanding -> current buf done
      if (wave == 3) asm volatile("s_waitcnt vmcnt(9)" ::: "memory");
      else           asm volatile("s_waitcnt vmcnt(8)" ::: "memory");
    } else {
      asm volatile("s_waitcnt vmcnt(0)" ::: "memory");
    }
    __builtin_amdgcn_s_barrier();          // raw barrier: prefetch stays in flight
    __builtin_amdgcn_sched_barrier(0);     // keep ds_reads below the barrier

    const unsigned short* Ac = &As[cur][0];
    const unsigned short* Bc = &Bs[cur][0];
    __builtin_amdgcn_s_setprio(1);
    #pragma unroll
    for (int k = 0; k < 3; ++k) {
      bf16x8 af[4], bfr[4];
      #pragma unroll
      for (int im = 0; im < 4; ++im) {
        int lrow = wm * 64 + im * 16 + rl + k;
        af[im] = *(const bf16x8*)&Ac[lrow * 32 + ((rq ^ SW(lrow)) * 8)];
      }
      #pragma unroll
      for (int in = 0; in < 4; ++in) {
        int R = k * 128 + wn * 64 + in * 16 + rl;
        bfr[in] = *(const bf16x8*)&Bc[R * 32 + ((rq ^ SW(R)) * 8)];
      }
      #pragma unroll
      for (int im = 0; im < 4; ++im)
        #pragma unroll
        for (int in = 0; in < 4; ++in)
          acc[im][in] = __builtin_amdgcn_mfma_f32_16x16x32_bf16(
              af[im], bfr[in], acc[im][in], 0, 0, 0);
    }
    __builtin_amdgcn_s_setprio(0);
    __builtin_amdgcn_s_barrier();          // all waves done reading buf[cur]
  }

  // ---- epilogue: bias + activation (C/D: col=lane&15, row=quad*4+reg)
  const bool is_tanh = (j0 >= 2 * HDIM);  // j-tile never straddles a gate boundary
  const int row_in_tile = (lane >> 4) * 4;
  float* gb = g + (size_t)b * TT * G3;
  #pragma unroll
  for (int in = 0; in < 4; ++in) {
    int j = j0 + wn * 64 + in * 16 + rl;
    float bv = bias[j];
    #pragma unroll
    for (int im = 0; im < 4; ++im) {
      int tl = wm * 64 + im * 16 + row_in_tile;
      #pragma unroll
      for (int r = 0; r < 4; ++r) {
        float s = acc[im][in][r] + bv;
        float v;
        if (is_tanh) v = 1.f - 2.f / (__expf(2.f * s) + 1.f);
        else         v = 1.f / (1.f + __expf(-s));
        gb[(size_t)(t0 + tl + r) * G3 + j] = v;
      }
    }
  }
}

// ---------- chunked parallel fo-pool ----------
// P1: per-(b,h,chunk) affine summary: c_end = A*c_start + B over TC steps.
__global__ __launch_bounds__(256) void pool_chunk_kernel(
    const float* __restrict__ g, float* __restrict__ a_arr,
    float* __restrict__ b_arr, int dir)
{
  int idx = blockIdx.x * 256 + threadIdx.x;   // ch*8192 + b*1024 + h
  int h  = idx & (HDIM - 1);
  int b  = (idx >> 10) & (BB - 1);
  int ch = idx >> 13;
  const float* gb = g + (size_t)b * TT * G3 + h;
  float a = 1.f, bacc = 0.f;
  #pragma unroll 8
  for (int s = ch * TC; s < ch * TC + TC; ++s) {
    int t = dir ? (TT - 1 - s) : s;
    size_t go = (size_t)t * G3;
    float f = gb[go];
    float z = gb[go + 2 * HDIM];
    bacc = f * bacc + (1.f - f) * z;
    a *= f;
  }
  a_arr[idx] = a;
  b_arr[idx] = bacc;
}

// P2: serial scan over chunk summaries -> c at chunk starts.
__global__ __launch_bounds__(256) void pool_scan_kernel(
    const float* __restrict__ a_arr, const float* __restrict__ b_arr,
    float* __restrict__ cinit)
{
  int bh = blockIdx.x * 256 + threadIdx.x;   // 0 .. B*H-1
  float c = 0.f;
  #pragma unroll
  for (int ch = 0; ch < NCH; ++ch) {
    cinit[ch * (BB * HDIM) + bh] = c;
    c = a_arr[ch * (BB * HDIM) + bh] * c + b_arr[ch * (BB * HDIM) + bh];
  }
}

// P3: re-run recurrence per chunk from cinit; write h; record t==T-1 state.
// OUT_BF16=1: write bf16 into time-PADDED layout [B][T+2][2H] at row t+1.
// OUT_BF16=0: write fp32 into unpadded [B][T][2H] (final output).
template<int OUT_BF16>
__global__ __launch_bounds__(256) void pool_apply_kernel(
    const float* __restrict__ g, const float* __restrict__ cinit,
    void* __restrict__ out, float* __restrict__ hid, float* __restrict__ cell,
    int dir, int layer)
{
  int idx = blockIdx.x * 256 + threadIdx.x;
  int h  = idx & (HDIM - 1);
  int b  = (idx >> 10) & (BB - 1);
  int ch = idx >> 13;
  const float* gb = g + (size_t)b * TT * G3 + h;
  const int coloff = dir * HDIM;
  float c = cinit[idx];
  #pragma unroll 8
  for (int s = ch * TC; s < ch * TC + TC; ++s) {
    int t = dir ? (TT - 1 - s) : s;
    size_t go = (size_t)t * G3;
    float f = gb[go];
    float o = gb[go + HDIM];
    float z = gb[go + 2 * HDIM];
    c = f * c + (1.f - f) * z;
    float hv = c * o;
    if (OUT_BF16) {
      size_t oo = ((size_t)b * TP + t + 1) * (2 * HDIM) + coloff + h;
      ((unsigned short*)out)[oo] = f2bf(hv);
    } else {
      size_t oo = ((size_t)b * TT + t) * (2 * HDIM) + coloff + h;
      ((float*)out)[oo] = hv;
    }
    if (t == TT - 1) {   // fwd: last step; rev: first step (rcells[:,-1])
      size_t off = (size_t)layer * (BB * 2 * HDIM) + (size_t)b * (2 * HDIM) + coloff + h;
      hid[off] = hv;
      cell[off] = c;
    }
  }
}

extern "C" void kernel_launch(void* const* d_in, const int* in_sizes, int n_in,
                              void* d_out, int out_size, void* d_ws, size_t ws_size,
                              hipStream_t stream) {
  const float* x   = (const float*)d_in[0];
  const float* w0f = (const float*)d_in[2];
  const float* b0f = (const float*)d_in[3];
  const float* w0r = (const float*)d_in[4];
  const float* b0r = (const float*)d_in[5];
  const float* w1f = (const float*)d_in[6];
  const float* b1f = (const float*)d_in[7];
  const float* w1r = (const float*)d_in[8];
  const float* b1r = (const float*)d_in[9];

  float* out1 = (float*)d_out;                       // B*T*2H fp32
  float* hid  = out1 + (size_t)BB * TT * 2 * HDIM;   // 4*B*H
  float* cell = hid + 4 * BB * HDIM;                 // 4*B*H

  // workspace layout (byte offsets, all 16B aligned).
  // NOTE: out0b/xb16 staging over-reads up to 14 rows past their logical end
  // (garbage LDS rows 130..143) -- they land in the NEXT ws buffer, so order
  // matters: g, out0b, xb16, wt, ... keeps all over-reads inside the workspace.
  char* ws = (char*)d_ws;
  size_t off = 0;
  float*          g     = (float*)(ws + off);  off += (size_t)BB * TT * G3 * 4;       // 100.7 MB
  unsigned short* out0b = (unsigned short*)(ws + off); off += (size_t)BB * TP * 2 * HDIM * 2; // 33.7 MB (padded)
  unsigned short* xb16  = (unsigned short*)(ws + off); off += (size_t)BB * TP * 1024 * 2;     // 16.8 MB (padded)
  unsigned short* wt    = (unsigned short*)(ws + off); off += (size_t)3 * G3 * 2048 * 2;      // 37.75 MB
  float* a_arr = (float*)(ws + off); off += (size_t)NCH * BB * HDIM * 4;  // 1 MB
  float* b_arr = (float*)(ws + off); off += (size_t)NCH * BB * HDIM * 4;  // 1 MB
  float* cinit = (float*)(ws + off); off += (size_t)NCH * BB * HDIM * 4;  // 1 MB

  dim3 blk(256);
  dim3 cgrd(8 * 24 * 8);                      // 1536, 1-D; XCD remap inside
  dim3 chgrd(NCH * BB * HDIM / 256);          // 1024
  dim3 scgrd(BB * HDIM / 256);                // 32

  // x -> padded bf16 (boundary rows zeroed in-kernel)
  cvt_x_pad_kernel<<<dim3(TP, BB), blk, 0, stream>>>(x, xb16);
  // zero boundary rows of out0b once (pool_apply never touches them)
  zero_pad_kernel<<<2 * BB * 2048 / 256, blk, 0, stream>>>(out0b);

  #define RUN_POOL(OUTB, outp, dir, layer)                                         \
    pool_chunk_kernel<<<chgrd, blk, 0, stream>>>(g, a_arr, b_arr, dir);            \
    pool_scan_kernel<<<scgrd, blk, 0, stream>>>(a_arr, b_arr, cinit);              \
    pool_apply_kernel<OUTB><<<chgrd, blk, 0, stream>>>(g, cinit, outp, hid, cell,  \
                                                       dir, layer);

  // ---- layer 0 (C=1024)
  cvt_w_kernel<1024><<<3 * G3 * 1024 / 256, blk, 0, stream>>>(w0f, wt);
  conv_mfma_kernel<1024><<<cgrd, blk, 0, stream>>>(xb16, wt, b0f, g);
  RUN_POOL(1, out0b, 0, 0)

  cvt_w_kernel<1024><<<3 * G3 * 1024 / 256, blk, 0, stream>>>(w0r, wt);
  conv_mfma_kernel<1024><<<cgrd, blk, 0, stream>>>(xb16, wt, b0r, g);
  RUN_POOL(1, out0b, 1, 0)

  // ---- layer 1 (C=2048)
  cvt_w_kernel<2048><<<3 * G3 * 2048 / 256, blk, 0, stream>>>(w1f, wt);
  conv_mfma_kernel<2048><<<cgrd, blk, 0, stream>>>(out0b, wt, b1f, g);
  RUN_POOL(0, out1, 0, 1)

  cvt_w_kernel<2048><<<3 * G3 * 2048 / 256, blk, 0, stream>>>(w1r, wt);
  conv_mfma_kernel<2048><<<cgrd, blk, 0, stream>>>(out0b, wt, b1r, g);
  RUN_POOL(0, out1, 1, 1)
  #undef RUN_POOL
}